// Round 5
// baseline (118.239 us; speedup 1.0000x reference)
//
#include <hip/hip_runtime.h>
#include <hip/hip_bf16.h>

// I2I CrossAttention + gate fusion, MI355X (gfx950).
// B=1, C=128, D*H*W = N = 8192, HEADS=4, DH=32.
// Round 5: attn occupancy doubled — 4 blocks/CU (grid 1024), block = 4 waves =
//          4 m-quarters over one 32-n tile; 32-m wave-steps; stage-only LDS
//          (32KB, combine reuses stage as scratch); V permute at 32-m
//          granularity; QKV projections fused into one kernel.

typedef __attribute__((ext_vector_type(4))) float f32x4;
typedef __attribute__((ext_vector_type(4))) unsigned u32x4;
typedef __attribute__((ext_vector_type(8))) short s16x8;
typedef __attribute__((ext_vector_type(4))) short s16x4;

#define MFMA_BF16(A,B,C) __builtin_amdgcn_mfma_f32_16x16x32_bf16((A),(B),(C),0,0,0)

static __device__ __forceinline__ float fexp2(float x){
  float r; asm("v_exp_f32 %0, %1" : "=v"(r) : "v"(x)); return r;
}
static __device__ __forceinline__ float frcp(float x){
  float r; asm("v_rcp_f32 %0, %1" : "=v"(r) : "v"(x)); return r;
}
static __device__ __forceinline__ unsigned cvtpk(float lo, float hi){
  unsigned r; asm("v_cvt_pk_bf16_f32 %0, %1, %2" : "=v"(r) : "v"(lo), "v"(hi)); return r;
}

__device__ __forceinline__ void gll16(const void* g, void* l){
  __builtin_amdgcn_global_load_lds(
      (const __attribute__((address_space(1))) void*)g,
      (__attribute__((address_space(3))) void*)l, 16, 0, 0);
}

// ---------------- weight prep: fp32 -> bf16 (Wq scaled) ----------------
__global__ __launch_bounds__(256) void wprep(
    const float* __restrict__ Wq, const float* __restrict__ Wk,
    const float* __restrict__ Wv, const float* __restrict__ Wo,
    const float* __restrict__ Wg1, const float* __restrict__ Wg2,
    __hip_bfloat16* __restrict__ out)
{
  int i = blockIdx.x*256 + threadIdx.x;              // 0..114687
  const float SCQ = 0.17677669529663689f * 1.44269504088896340f;
  float v;
  if      (i < 16384) v = Wq[i]*SCQ;
  else if (i < 32768) v = Wk[i-16384];
  else if (i < 49152) v = Wv[i-32768];
  else if (i < 65536) v = Wo[i-49152];
  else if (i < 98304) v = Wg1[i-65536];
  else                v = Wg2[i-98304];
  out[i] = __float2bfloat16(v);
}

// ------------- transpose [128][8192] fp32 -> [8192][128] bf16 -------------
__global__ __launch_bounds__(256) void transpose_to_bf16(
    const float* __restrict__ in, __hip_bfloat16* __restrict__ out)
{
  __shared__ __hip_bfloat16 tile[64][128];
  int tid = threadIdx.x;
  int n0 = blockIdx.x*64;
  int cq = tid>>4;
  int nq = (tid&15)*4;
  #pragma unroll
  for (int r=0;r<8;r++){
    int c = r*16 + cq;
    f32x4 val = *(const f32x4*)&in[c*8192 + n0 + nq];
    #pragma unroll
    for (int i=0;i<4;i++){
      int n = nq + i;
      tile[n][c ^ ((n&7)<<4)] = __float2bfloat16(val[i]);
    }
  }
  __syncthreads();
  int row = tid>>2;
  int cb  = (tid&3)*32;
  #pragma unroll
  for (int k=0;k<4;k++){
    int c0 = cb + 8*k;
    s16x8 v = *(const s16x8*)&tile[row][c0 ^ ((row&7)<<4)];
    *(s16x8*)&out[(n0+row)*128 + c0] = v;
  }
}

// ---------------- fused Q/K/V projection (blockIdx.y selects) ----------------
// y=0: QT[n][128] from F1T (bias*SCQ); y=1: KT[n][128] from F2T;
// y=2: Vp[o][8192] from F2T, 32-m-block permute + bank XOR pre-applied.
__global__ __launch_bounds__(256) void qkv(
    const __hip_bfloat16* __restrict__ F1T, const __hip_bfloat16* __restrict__ F2T,
    const __hip_bfloat16* __restrict__ Wall,
    const float* __restrict__ bq, const float* __restrict__ bk,
    const float* __restrict__ bv,
    __hip_bfloat16* __restrict__ QT, __hip_bfloat16* __restrict__ KT,
    __hip_bfloat16* __restrict__ Vp)
{
  const float SCQ = 0.17677669529663689f * 1.44269504088896340f;
  int y = blockIdx.y;
  const __hip_bfloat16* A  = (y==0) ? F1T : F2T;
  const __hip_bfloat16* Bw = Wall + y*16384;
  const float* bias = (y==0) ? bq : (y==1) ? bk : bv;
  float bscale = (y==0) ? SCQ : 1.f;

  int tid = threadIdx.x;
  int w = tid>>6, lane = tid&63, g = lane>>4, ln = lane&15;
  int n0 = blockIdx.x*16, o0 = w*32;
  f32x4 acc0 = {0.f,0.f,0.f,0.f}, acc1 = {0.f,0.f,0.f,0.f};
  #pragma unroll
  for (int ck=0; ck<4; ck++){
    s16x8 af  = *(const s16x8*)&A[(n0+ln)*128 + ck*32 + 8*g];
    s16x8 bf0 = *(const s16x8*)&Bw[(o0+ln)*128 + ck*32 + 8*g];
    s16x8 bf1 = *(const s16x8*)&Bw[(o0+16+ln)*128 + ck*32 + 8*g];
    if (y == 2){
      acc0 = MFMA_BF16(bf0, af, acc0);
      acc1 = MFMA_BF16(bf1, af, acc1);
    } else {
      acc0 = MFMA_BF16(af, bf0, acc0);
      acc1 = MFMA_BF16(af, bf1, acc1);
    }
  }
  if (y == 2){
    // col = blk*32 + (q ^ ((o>>1)&3))*8 + hb*4 + i  for m31 = 16hb+4q+i
    #pragma unroll
    for (int to=0; to<2; to++){
      f32x4 a = to ? acc1 : acc0;
      #pragma unroll
      for (int r=0;r<4;r++){
        int o = o0 + 16*to + 4*g + r;
        int n = n0 + ln;
        int m31 = n & 31;
        int q  = (m31>>2)&3, hb = m31>>4, i = m31&3;
        int col = (n>>5)*32 + ((q ^ ((o>>1)&3))<<3) + hb*4 + i;
        Vp[(size_t)o*8192 + col] = __float2bfloat16(a[r] + bias[o]);
      }
    }
  } else {
    __hip_bfloat16* outb = (y==0) ? QT : KT;
    float b0 = bias[o0+ln]*bscale, b1 = bias[o0+16+ln]*bscale;
    #pragma unroll
    for (int to=0; to<2; to++){
      f32x4 a = to ? acc1 : acc0;
      float bb = to ? b1 : b0;
      int o = o0 + 16*to + ln;
      #pragma unroll
      for (int r=0;r<4;r++){
        int n = n0 + 4*g + r;
        outb[n*128 + o] = __float2bfloat16(a[r] + bb);
      }
    }
  }
}

// ---------------- generic transposed-output channel-mix GEMM ----------------
// ep: 0 = bf16 [n][128]; 2 = relu bf16 [n][128];
//     3 = sigmoid gate fused combine -> fp32 out [c][n]
template<int KCH, int SPLIT>
__global__ __launch_bounds__(256) void gemmT(
    const __hip_bfloat16* __restrict__ A1, const __hip_bfloat16* __restrict__ A2,
    const __hip_bfloat16* __restrict__ Bw, const int bstride,
    const float* __restrict__ bias, const float bscale,
    __hip_bfloat16* __restrict__ outb, const int ep,
    const float* __restrict__ xf1, const __hip_bfloat16* __restrict__ xao,
    float* __restrict__ xout)
{
  int tid = threadIdx.x;
  int w = tid>>6, lane = tid&63, g = lane>>4, ln = lane&15;
  int n0 = blockIdx.x*16, o0 = w*32;
  f32x4 acc0 = {0.f,0.f,0.f,0.f}, acc1 = {0.f,0.f,0.f,0.f};
  #pragma unroll
  for (int ck=0; ck<KCH; ck++){
    const __hip_bfloat16* As = (ck < SPLIT) ? A1 : A2;
    int cb = ((ck < SPLIT) ? ck : (ck-SPLIT))*32;
    s16x8 af  = *(const s16x8*)&As[(n0+ln)*128 + cb + 8*g];
    s16x8 bf0 = *(const s16x8*)&Bw[(o0+ln)*bstride + ck*32 + 8*g];
    s16x8 bf1 = *(const s16x8*)&Bw[(o0+16+ln)*bstride + ck*32 + 8*g];
    acc0 = MFMA_BF16(af, bf0, acc0);
    acc1 = MFMA_BF16(af, bf1, acc1);
  }
  float b0 = bias[o0+ln]*bscale, b1 = bias[o0+16+ln]*bscale;
  #pragma unroll
  for (int to=0; to<2; to++){
    f32x4 a = to ? acc1 : acc0;
    float bb = to ? b1 : b0;
    int o = o0 + 16*to + ln;
    #pragma unroll
    for (int r=0;r<4;r++){
      int n = n0 + 4*g + r;
      float v = a[r] + bb;
      if (ep == 2) v = fmaxf(v, 0.f);
      if (ep == 3){
        float gt = frcp(1.f + fexp2(-1.44269504f*v));
        float f1 = xf1[(size_t)o*8192 + n];
        float ao = __bfloat162float(xao[n*128 + o]);
        xout[(size_t)o*8192 + n] = gt*f1 + (1.f - gt)*ao;
      } else {
        outb[n*128 + o] = __float2bfloat16(v);
      }
    }
  }
}

// ---------------- fused attention: 4 m-quarter waves, 32-n blocks ----------------
// Block: 256 threads = 4 waves, wave w = m-quarter qh. Grid (256,4) = 1024 blocks
// = 4 blocks/CU. Per step each wave: 32 m x 32 n. 2x16KB stage, depth-1 prefetch.
__global__ __launch_bounds__(256, 4) void attn5(
    const __hip_bfloat16* __restrict__ QT, const __hip_bfloat16* __restrict__ KT,
    const __hip_bfloat16* __restrict__ Vp, __hip_bfloat16* __restrict__ OT)
{
  __shared__ short stage[2][8192];     // 2 x 16KB: per wave w: K(2KB) V(2KB)

  const int tid = threadIdx.x;
  const int w = tid>>6, lane = tid&63, g = lane>>4, ln = lane&15;
  const int h = blockIdx.y;
  const int nbase = blockIdx.x*32;

  const __hip_bfloat16* Kh = KT + h*32;
  const __hip_bfloat16* Vh = Vp + (size_t)(h*32)*8192;

  // Q fragments (Q pre-scaled by SCALE*log2e)
  s16x8 qf[2];
  qf[0] = *(const s16x8*)&QT[(size_t)(nbase+ln)*128 + h*32 + 8*g];
  qf[1] = *(const s16x8*)&QT[(size_t)(nbase+16+ln)*128 + h*32 + 8*g];

  // ---- staging: wave w covers its own quarter: segs 4w..4w+3 (1KB each) ----
  // u=0,1: K rows u*16+(l>>2) (src chunk-swizzled); u=2,3: V c-rows, linear copy
  const __hip_bfloat16* gp[4];
  int gstep[4], ldoff[4];
  #pragma unroll
  for (int u=0; u<4; u++){
    if (u < 2){
      int m0 = w*2048 + u*16 + (lane>>2);
      int gk = (lane&3) ^ ((lane>>3)&3);              // source-side chunk swizzle
      gp[u] = &Kh[(size_t)m0*128 + 8*gk];
      gstep[u] = 32*128;
    } else {
      int c = (u-2)*16 + (lane>>2);
      gp[u] = &Vh[(size_t)c*8192 + w*2048 + 8*(lane&3)];
      gstep[u] = 32;
    }
    ldoff[u] = (4*w+u)*512;                           // shorts
  }
  short* sb = &stage[0][0];

  #define ISSUE(OFF) { \
    _Pragma("unroll") \
    for (int u=0;u<4;u++){ gll16(gp[u], sb + (OFF) + ldoff[u]); gp[u] += gstep[u]; } }

  const int kchunk = (g ^ ((ln>>1)&3))<<3;            // shorts, within 64B rows

  const u32x4 onesw = {0x3F803F80u,0x3F803F80u,0x3F803F80u,0x3F803F80u};
  const s16x8 onesf = __builtin_bit_cast(s16x8, onesw);

  f32x4 acc[2][2];                                     // [ct][j]
  #pragma unroll
  for (int t=0;t<2;t++){ acc[t][0]=(f32x4){0,0,0,0}; acc[t][1]=(f32x4){0,0,0,0}; }
  f32x4 accS[2] = {(f32x4){0,0,0,0},(f32x4){0,0,0,0}};

  ISSUE(0);
  for (int t=0; t<64; ++t){
    asm volatile("s_waitcnt vmcnt(0)" ::: "memory");
    __builtin_amdgcn_s_barrier();
    const int cur = (t&1)<<13;
    if (t < 63) ISSUE(8192 - cur);

    const short* Kl = sb + cur + w*2048;
    const short* Vl = Kl + 1024;

    // K fragments + S^T MFMAs: lane holds S^T[m=16r+4g+reg][n_j]
    s16x8 kf0 = *(const s16x8*)&Kl[        ln*32 + kchunk];
    s16x8 kf1 = *(const s16x8*)&Kl[ 512 +  ln*32 + kchunk];
    f32x4 s[2][2];
    __builtin_amdgcn_s_setprio(1);
    {
      f32x4 z = {0.f,0.f,0.f,0.f};
      s[0][0] = MFMA_BF16(kf0, qf[0], z);
      s[0][1] = MFMA_BF16(kf0, qf[1], z);
      s[1][0] = MFMA_BF16(kf1, qf[0], z);
      s[1][1] = MFMA_BF16(kf1, qf[1], z);
    }
    __builtin_amdgcn_s_setprio(0);

    // V fragments: single b128 each (global side pre-permuted + bank-XORed)
    s16x8 vf0 = *(const s16x8*)&Vl[       ln*32 + kchunk];
    s16x8 vf1 = *(const s16x8*)&Vl[512 +  ln*32 + kchunk];

    // softmax numerator, fixed max=0; raw v_exp + v_cvt_pk_bf16_f32
    s16x8 pb[2];                                       // [j]
    #pragma unroll
    for (int j=0;j<2;j++){
      float p0 = fexp2(s[0][j][0]), p1 = fexp2(s[0][j][1]);
      float p2 = fexp2(s[0][j][2]), p3 = fexp2(s[0][j][3]);
      float q0 = fexp2(s[1][j][0]), q1 = fexp2(s[1][j][1]);
      float q2 = fexp2(s[1][j][2]), q3 = fexp2(s[1][j][3]);
      u32x4 pw;
      pw[0] = cvtpk(p0,p1); pw[1] = cvtpk(p2,p3);
      pw[2] = cvtpk(q0,q1); pw[3] = cvtpk(q2,q3);
      pb[j] = __builtin_bit_cast(s16x8, pw);
    }

    // PV + psum (ones-MFMA)
    __builtin_amdgcn_s_setprio(1);
    acc[0][0] = MFMA_BF16(vf0, pb[0], acc[0][0]);
    acc[0][1] = MFMA_BF16(vf0, pb[1], acc[0][1]);
    acc[1][0] = MFMA_BF16(vf1, pb[0], acc[1][0]);
    acc[1][1] = MFMA_BF16(vf1, pb[1], acc[1][1]);
    accS[0]   = MFMA_BF16(onesf, pb[0], accS[0]);
    accS[1]   = MFMA_BF16(onesf, pb[1], accS[1]);
    __builtin_amdgcn_s_setprio(0);
  }
  #undef ISSUE

  // ---- 4-way combine through stage scratch (buf0 reuse) ----
  float* scr = (float*)sb;                             // 3 x 64 x 20 floats
  __syncthreads();
  if (w != 0){
    int base = ((w-1)*64 + lane)*20;
    #pragma unroll
    for (int ct=0; ct<2; ct++)
      #pragma unroll
      for (int j=0;j<2;j++)
        *(f32x4*)&scr[base + (ct*2+j)*4] = acc[ct][j];
    scr[base+16] = accS[0][0];
    scr[base+17] = accS[1][0];
  }
  __syncthreads();
  if (w == 0){
    float ps0 = accS[0][0], ps1 = accS[1][0];
    #pragma unroll
    for (int q=0; q<3; q++){
      ps0 += scr[(q*64+lane)*20+16];
      ps1 += scr[(q*64+lane)*20+17];
    }
    float inv[2] = { frcp(ps0), frcp(ps1) };
    #pragma unroll
    for (int ct=0; ct<2; ct++){
      #pragma unroll
      for (int j=0;j<2;j++){
        f32x4 o = acc[ct][j];
        #pragma unroll
        for (int q=0; q<3; q++)
          o += *(const f32x4*)&scr[(q*64+lane)*20 + (ct*2+j)*4];
        unsigned lo = cvtpk(o[0]*inv[j], o[1]*inv[j]);
        unsigned hi = cvtpk(o[2]*inv[j], o[3]*inv[j]);
        unsigned long long pk = ((unsigned long long)hi<<32) | lo;
        *(unsigned long long*)&OT[(size_t)(nbase+16*j+ln)*128 + h*32 + 16*ct + 4*g] = pk;
      }
    }
  }
}

extern "C" void kernel_launch(void* const* d_in, const int* in_sizes, int n_in,
                              void* d_out, int out_size, void* d_ws, size_t ws_size,
                              hipStream_t stream)
{
  const float* feat1 = (const float*)d_in[0];
  const float* feat2 = (const float*)d_in[1];
  const float* Wq = (const float*)d_in[2];  const float* bq = (const float*)d_in[3];
  const float* Wk = (const float*)d_in[4];  const float* bk = (const float*)d_in[5];
  const float* Wv = (const float*)d_in[6];  const float* bv = (const float*)d_in[7];
  const float* Wo = (const float*)d_in[8];  const float* bo = (const float*)d_in[9];
  const float* Wg1 = (const float*)d_in[10]; const float* bg1 = (const float*)d_in[11];
  const float* Wg2 = (const float*)d_in[12]; const float* bg2 = (const float*)d_in[13];

  __hip_bfloat16* WQb  = (__hip_bfloat16*)d_ws;
  __hip_bfloat16* WKb  = WQb + 16384;
  __hip_bfloat16* WVb  = WQb + 32768;
  __hip_bfloat16* WOb  = WQb + 49152;
  __hip_bfloat16* WG1b = WQb + 65536;
  __hip_bfloat16* WG2b = WQb + 98304;
  __hip_bfloat16* F1T  = WQb + 114688;
  __hip_bfloat16* F2T  = F1T + 1048576;
  __hip_bfloat16* QT   = F1T + 2*1048576;
  __hip_bfloat16* KT   = F1T + 3*1048576;
  __hip_bfloat16* Vbf  = F1T + 4*1048576;
  __hip_bfloat16* OT   = F1T + 5*1048576;
  __hip_bfloat16* AOT  = F1T + 6*1048576;
  __hip_bfloat16* G1T  = F1T + 7*1048576;

  wprep<<<448,256,0,stream>>>(Wq,Wk,Wv,Wo,Wg1,Wg2,WQb);
  transpose_to_bf16<<<128,256,0,stream>>>(feat1, F1T);
  transpose_to_bf16<<<128,256,0,stream>>>(feat2, F2T);
  qkv<<<dim3(512,3),256,0,stream>>>(F1T,F2T,WQb,bq,bk,bv,QT,KT,Vbf);
  attn5<<<dim3(256,4),256,0,stream>>>(QT,KT,Vbf,OT);
  gemmT<4,4><<<512,256,0,stream>>>(OT ,OT ,WOb ,128,bo ,1.f, AOT,0,nullptr,nullptr,nullptr);
  gemmT<8,4><<<512,256,0,stream>>>(AOT,F1T,WG1b,256,bg1,1.f, G1T,2,nullptr,nullptr,nullptr);
  gemmT<4,4><<<512,256,0,stream>>>(G1T,G1T,WG2b,128,bg2,1.f, nullptr,3,feat1,AOT,(float*)d_out);
}

// Round 7
// 104.496 us; speedup vs baseline: 1.1315x; 1.1315x over previous
//
#include <hip/hip_runtime.h>
#include <hip/hip_bf16.h>

// I2I CrossAttention + gate fusion, MI355X (gfx950).
// B=1, C=128, D*H*W = N = 8192, HEADS=4, DH=32.
// Round 7: recovery round — compose only validated pieces:
//   attn = R4 body (passed, 63us) + R3 3-buffer vmcnt(4) schedule (passed);
//   fusions from R5 (passed): qkv 1 kernel, transposes 1 kernel, gate+combine.

typedef __attribute__((ext_vector_type(4))) float f32x4;
typedef __attribute__((ext_vector_type(4))) unsigned u32x4;
typedef __attribute__((ext_vector_type(8))) short s16x8;
typedef __attribute__((ext_vector_type(4))) short s16x4;

#define MFMA_BF16(A,B,C) __builtin_amdgcn_mfma_f32_16x16x32_bf16((A),(B),(C),0,0,0)

static __device__ __forceinline__ float fexp2(float x){
  float r; asm("v_exp_f32 %0, %1" : "=v"(r) : "v"(x)); return r;
}
static __device__ __forceinline__ float frcp(float x){
  float r; asm("v_rcp_f32 %0, %1" : "=v"(r) : "v"(x)); return r;
}
static __device__ __forceinline__ unsigned cvtpk(float lo, float hi){
  unsigned r; asm("v_cvt_pk_bf16_f32 %0, %1, %2" : "=v"(r) : "v"(lo), "v"(hi)); return r;
}

__device__ __forceinline__ void gll16(const void* g, void* l){
  __builtin_amdgcn_global_load_lds(
      (const __attribute__((address_space(1))) void*)g,
      (__attribute__((address_space(3))) void*)l, 16, 0, 0);
}

// ---------------- weight prep: fp32 -> bf16 (Wq scaled) ----------------
__global__ __launch_bounds__(256) void wprep(
    const float* __restrict__ Wq, const float* __restrict__ Wk,
    const float* __restrict__ Wv, const float* __restrict__ Wo,
    const float* __restrict__ Wg1, const float* __restrict__ Wg2,
    __hip_bfloat16* __restrict__ out)
{
  int i = blockIdx.x*256 + threadIdx.x;              // 0..114687
  const float SCQ = 0.17677669529663689f * 1.44269504088896340f;
  float v;
  if      (i < 16384) v = Wq[i]*SCQ;
  else if (i < 32768) v = Wk[i-16384];
  else if (i < 49152) v = Wv[i-32768];
  else if (i < 65536) v = Wo[i-49152];
  else if (i < 98304) v = Wg1[i-65536];
  else                v = Wg2[i-98304];
  out[i] = __float2bfloat16(v);
}

// ------- transpose [128][8192] fp32 -> [8192][128] bf16 (y: feat1/feat2) -------
__global__ __launch_bounds__(256) void transpose2(
    const float* __restrict__ f1, const float* __restrict__ f2,
    __hip_bfloat16* __restrict__ F1T, __hip_bfloat16* __restrict__ F2T)
{
  const float* in = blockIdx.y ? f2 : f1;
  __hip_bfloat16* out = blockIdx.y ? F2T : F1T;
  __shared__ __hip_bfloat16 tile[64][128];
  int tid = threadIdx.x;
  int n0 = blockIdx.x*64;
  int cq = tid>>4;
  int nq = (tid&15)*4;
  #pragma unroll
  for (int r=0;r<8;r++){
    int c = r*16 + cq;
    f32x4 val = *(const f32x4*)&in[c*8192 + n0 + nq];
    #pragma unroll
    for (int i=0;i<4;i++){
      int n = nq + i;
      tile[n][c ^ ((n&7)<<4)] = __float2bfloat16(val[i]);
    }
  }
  __syncthreads();
  int row = tid>>2;
  int cb  = (tid&3)*32;
  #pragma unroll
  for (int k=0;k<4;k++){
    int c0 = cb + 8*k;
    s16x8 v = *(const s16x8*)&tile[row][c0 ^ ((row&7)<<4)];
    *(s16x8*)&out[(n0+row)*128 + c0] = v;
  }
}

// ---------------- fused Q/K/V projection (blockIdx.y selects) ----------------
// y=0: QT[n][128] from F1T (bias*SCQ); y=1: KT[n][128] from F2T;
// y=2: Vp[o][8192] from F2T, R4's 64-m-block permute + bank XOR pre-applied.
__global__ __launch_bounds__(256) void qkv(
    const __hip_bfloat16* __restrict__ F1T, const __hip_bfloat16* __restrict__ F2T,
    const __hip_bfloat16* __restrict__ Wall,
    const float* __restrict__ bq, const float* __restrict__ bk,
    const float* __restrict__ bv,
    __hip_bfloat16* __restrict__ QT, __hip_bfloat16* __restrict__ KT,
    __hip_bfloat16* __restrict__ Vp)
{
  const float SCQ = 0.17677669529663689f * 1.44269504088896340f;
  int y = blockIdx.y;
  const __hip_bfloat16* A  = (y==0) ? F1T : F2T;
  const __hip_bfloat16* Bw = Wall + y*16384;
  const float* bias = (y==0) ? bq : (y==1) ? bk : bv;
  float bscale = (y==0) ? SCQ : 1.f;

  int tid = threadIdx.x;
  int w = tid>>6, lane = tid&63, g = lane>>4, ln = lane&15;
  int n0 = blockIdx.x*16, o0 = w*32;
  f32x4 acc0 = {0.f,0.f,0.f,0.f}, acc1 = {0.f,0.f,0.f,0.f};
  #pragma unroll
  for (int ck=0; ck<4; ck++){
    s16x8 af  = *(const s16x8*)&A[(n0+ln)*128 + ck*32 + 8*g];
    s16x8 bf0 = *(const s16x8*)&Bw[(o0+ln)*128 + ck*32 + 8*g];
    s16x8 bf1 = *(const s16x8*)&Bw[(o0+16+ln)*128 + ck*32 + 8*g];
    if (y == 2){
      acc0 = MFMA_BF16(bf0, af, acc0);
      acc1 = MFMA_BF16(bf1, af, acc1);
    } else {
      acc0 = MFMA_BF16(af, bf0, acc0);
      acc1 = MFMA_BF16(af, bf1, acc1);
    }
  }
  if (y == 2){
    // R4-validated permute: granule Gx = (4*(m63>>5) | q) ^ (o&7), pos hb*4+i
    #pragma unroll
    for (int to=0; to<2; to++){
      f32x4 a = to ? acc1 : acc0;
      #pragma unroll
      for (int r=0;r<4;r++){
        int o = o0 + 16*to + 4*g + r;
        int n = n0 + ln;
        int m63 = n & 63, blk = n >> 6;
        int Gx = (((m63>>5)<<2) | ((m63>>2)&3)) ^ (o & 7);
        int col = blk*64 + Gx*8 + ((m63>>4)&1)*4 + (m63&3);
        Vp[(size_t)o*8192 + col] = __float2bfloat16(a[r] + bias[o]);
      }
    }
  } else {
    __hip_bfloat16* outb = (y==0) ? QT : KT;
    float b0 = bias[o0+ln]*bscale, b1 = bias[o0+16+ln]*bscale;
    #pragma unroll
    for (int to=0; to<2; to++){
      f32x4 a = to ? acc1 : acc0;
      float bb = to ? b1 : b0;
      int o = o0 + 16*to + ln;
      #pragma unroll
      for (int r=0;r<4;r++){
        int n = n0 + 4*g + r;
        outb[n*128 + o] = __float2bfloat16(a[r] + bb);
      }
    }
  }
}

// ---------------- generic transposed-output channel-mix GEMM ----------------
// ep: 0 = bf16 [n][128]; 2 = relu bf16 [n][128];
//     3 = sigmoid gate fused combine -> fp32 out [c][n]
template<int KCH, int SPLIT>
__global__ __launch_bounds__(256) void gemmT(
    const __hip_bfloat16* __restrict__ A1, const __hip_bfloat16* __restrict__ A2,
    const __hip_bfloat16* __restrict__ Bw, const int bstride,
    const float* __restrict__ bias, const float bscale,
    __hip_bfloat16* __restrict__ outb, const int ep,
    const float* __restrict__ xf1, const __hip_bfloat16* __restrict__ xao,
    float* __restrict__ xout)
{
  int tid = threadIdx.x;
  int w = tid>>6, lane = tid&63, g = lane>>4, ln = lane&15;
  int n0 = blockIdx.x*16, o0 = w*32;
  f32x4 acc0 = {0.f,0.f,0.f,0.f}, acc1 = {0.f,0.f,0.f,0.f};
  #pragma unroll
  for (int ck=0; ck<KCH; ck++){
    const __hip_bfloat16* As = (ck < SPLIT) ? A1 : A2;
    int cb = ((ck < SPLIT) ? ck : (ck-SPLIT))*32;
    s16x8 af  = *(const s16x8*)&As[(n0+ln)*128 + cb + 8*g];
    s16x8 bf0 = *(const s16x8*)&Bw[(o0+ln)*bstride + ck*32 + 8*g];
    s16x8 bf1 = *(const s16x8*)&Bw[(o0+16+ln)*bstride + ck*32 + 8*g];
    acc0 = MFMA_BF16(af, bf0, acc0);
    acc1 = MFMA_BF16(af, bf1, acc1);
  }
  float b0 = bias[o0+ln]*bscale, b1 = bias[o0+16+ln]*bscale;
  #pragma unroll
  for (int to=0; to<2; to++){
    f32x4 a = to ? acc1 : acc0;
    float bb = to ? b1 : b0;
    int o = o0 + 16*to + ln;
    #pragma unroll
    for (int r=0;r<4;r++){
      int n = n0 + 4*g + r;
      float v = a[r] + bb;
      if (ep == 2) v = fmaxf(v, 0.f);
      if (ep == 3){
        float gt = frcp(1.f + fexp2(-1.44269504f*v));
        float f1 = xf1[(size_t)o*8192 + n];
        float ao = __bfloat162float(xao[n*128 + o]);
        xout[(size_t)o*8192 + n] = gt*f1 + (1.f - gt)*ao;
      } else {
        outb[n*128 + o] = __float2bfloat16(v);
      }
    }
  }
}

// ---------------- fused attention: R4 body + R3 3-buffer vmcnt(4) ----------------
// Block: 256 threads = 4 waves; wave w: nt = w&1 (32-n tile), mh = w>>1 (m-half).
// Grid (128,4) = 512 blocks (2/CU). 3 x 16KB stage buffers, loads 2 steps in flight.
__global__ __launch_bounds__(256, 2) void attn8(
    const __hip_bfloat16* __restrict__ QT, const __hip_bfloat16* __restrict__ KT,
    const __hip_bfloat16* __restrict__ Vp, __hip_bfloat16* __restrict__ OT)
{
  __shared__ short stage[3][8192];     // [buf][16KB]: K0 V0 K1 V1 (4KB each)
  __shared__ float cmb[2][64][16];     // mh=1 partial accs
  __shared__ float cps[2][2][16];      // mh=1 partial psums

  const int tid = threadIdx.x;
  const int w = tid>>6, lane = tid&63, g = lane>>4, ln = lane&15;
  const int nt = w&1, mh = w>>1;
  const int h = blockIdx.y;
  const int nbase = blockIdx.x*64 + nt*32;

  const __hip_bfloat16* Kh = KT + h*32;
  const __hip_bfloat16* Vh = Vp + (size_t)(h*32)*8192;

  // Q fragments (Q pre-scaled by SCALE*log2e)
  s16x8 qf[2];
  qf[0] = *(const s16x8*)&QT[(size_t)(nbase+ln)*128 + h*32 + 8*g];
  qf[1] = *(const s16x8*)&QT[(size_t)(nbase+16+ln)*128 + h*32 + 8*g];

  // ---- staging sources: thread covers segments 4w..4w+3 (16 x 1KB) ----
  // seg 0-3: K(mh0) rows seg*16.. ; 4-7: V(mh0, linear: Vp pre-permuted);
  // 8-15: same for mh1. gll dest = uniform base (+ lane*16B by HW).
  const __hip_bfloat16* gp[4];
  int gstep[4], ldoff[4];
  #pragma unroll
  for (int u=0; u<4; u++){
    int seg = 4*w + u;
    int smh = seg>>3, rem = seg&7, isV = rem>>2, sr = rem&3;
    if (!isV){
      int row = sr*16 + (lane>>2);
      int gk  = (lane&3) ^ ((lane>>3)&3);             // source-side K swizzle
      gp[u] = &Kh[(size_t)(smh*4096 + row)*128 + 8*gk];
      gstep[u] = 64*128;
    } else {
      int c = sr*8 + (lane>>3);                        // linear V copy
      gp[u] = &Vh[(size_t)c*8192 + smh*4096 + 8*(lane&7)];
      gstep[u] = 64;
    }
    ldoff[u] = seg*512;                                // shorts (1 KB per seg)
  }
  short* sb = &stage[0][0];

  #define ISSUE(OFF) { \
    _Pragma("unroll") \
    for (int u=0;u<4;u++){ gll16(gp[u], sb + (OFF) + ldoff[u]); gp[u] += gstep[u]; } }

  // ---- LDS read offsets (shorts) ----
  const int kloff = ln*32 + ((g ^ ((ln>>1)&3))<<3);    // + r*512, within K half
  int voff[2];                                         // [kk], + (16ct+ln)*64
  voff[0] = 8*((g  ) ^ (ln&7));
  voff[1] = 8*((g+4) ^ (ln&7));

  const u32x4 onesw = {0x3F803F80u,0x3F803F80u,0x3F803F80u,0x3F803F80u};
  const s16x8 onesf = __builtin_bit_cast(s16x8, onesw);

  f32x4 acc[2][2];                                     // [ct][j]
  #pragma unroll
  for (int t=0;t<2;t++){ acc[t][0]=(f32x4){0,0,0,0}; acc[t][1]=(f32x4){0,0,0,0}; }
  f32x4 accS[2] = {(f32x4){0,0,0,0},(f32x4){0,0,0,0}};  // ones-MFMA psum

  // prologue: stage steps 0,1 into bufs 0,1 (8 loads in flight per thread)
  ISSUE(0);
  ISSUE(8192);

  unsigned roff = 0, ioff = 16384;
  for (int t=0; t<64; ++t){
    // buffer(t) ready: wait down to 4 outstanding (t+1's loads stay in flight)
    asm volatile("s_waitcnt vmcnt(4)" ::: "memory");
    __builtin_amdgcn_s_barrier();
    // issue step t+2 into the buffer read at t-1 (block-wide done per barrier);
    // tail issues read valid workspace and land in never-read buffers.
    ISSUE(ioff);
    ioff = (ioff == 16384u) ? 0u : ioff + 8192u;

    const short* Kl = sb + roff + mh*4096;
    const short* Vl = Kl + 2048;
    roff = (roff == 16384u) ? 0u : roff + 8192u;

    // K fragments + S^T MFMAs: lane holds S^T[m=16r+4g+reg][n_j]
    s16x8 kf[4];
    #pragma unroll
    for (int r=0;r<4;r++)
      kf[r] = *(const s16x8*)&Kl[r*512 + kloff];
    f32x4 s[4][2];
    __builtin_amdgcn_s_setprio(1);
    #pragma unroll
    for (int r=0;r<4;r++){
      f32x4 z = {0.f,0.f,0.f,0.f};
      s[r][0] = MFMA_BF16(kf[r], qf[0], z);
      s[r][1] = MFMA_BF16(kf[r], qf[1], z);
    }
    __builtin_amdgcn_s_setprio(0);

    // V fragments: single b128 each (global side pre-permuted + bank-XORed)
    s16x8 vf[2][2];                                    // [kk][ct]
    #pragma unroll
    for (int kk=0; kk<2; kk++)
      #pragma unroll
      for (int ct=0; ct<2; ct++)
        vf[kk][ct] = *(const s16x8*)&Vl[(16*ct+ln)*64 + voff[kk]];

    // softmax numerator, fixed max=0; raw v_exp + v_cvt_pk_bf16_f32
    s16x8 pb[2][2];                                    // [kk][j]
    #pragma unroll
    for (int j=0;j<2;j++){
      #pragma unroll
      for (int kk=0; kk<2; kk++){
        float p0 = fexp2(s[2*kk  ][j][0]), p1 = fexp2(s[2*kk  ][j][1]);
        float p2 = fexp2(s[2*kk  ][j][2]), p3 = fexp2(s[2*kk  ][j][3]);
        float q0 = fexp2(s[2*kk+1][j][0]), q1 = fexp2(s[2*kk+1][j][1]);
        float q2 = fexp2(s[2*kk+1][j][2]), q3 = fexp2(s[2*kk+1][j][3]);
        u32x4 pw;
        pw[0] = cvtpk(p0,p1); pw[1] = cvtpk(p2,p3);
        pw[2] = cvtpk(q0,q1); pw[3] = cvtpk(q2,q3);
        pb[kk][j] = __builtin_bit_cast(s16x8, pw);
      }
    }

    // PV + psum (ones-MFMA): all on the matrix pipe
    __builtin_amdgcn_s_setprio(1);
    #pragma unroll
    for (int kk=0; kk<2; kk++){
      #pragma unroll
      for (int ct=0; ct<2; ct++){
        acc[ct][0] = MFMA_BF16(vf[kk][ct], pb[kk][0], acc[ct][0]);
        acc[ct][1] = MFMA_BF16(vf[kk][ct], pb[kk][1], acc[ct][1]);
      }
      accS[0] = MFMA_BF16(onesf, pb[kk][0], accS[0]);
      accS[1] = MFMA_BF16(onesf, pb[kk][1], accS[1]);
    }
    __builtin_amdgcn_s_setprio(0);
  }
  #undef ISSUE

  // ---- combine m-halves; accS[j][0] == psum for n = nbase+16j+ln (all lanes)
  if (mh == 1){
    #pragma unroll
    for (int ct=0; ct<2; ct++)
      #pragma unroll
      for (int j=0;j<2;j++)
        *(f32x4*)&cmb[nt][lane][(ct*2+j)*4] = acc[ct][j];
    if (lane < 16){ cps[nt][0][lane] = accS[0][0]; cps[nt][1][lane] = accS[1][0]; }
  }
  __syncthreads();
  if (mh == 0){
    float inv[2];
    inv[0] = frcp(accS[0][0] + cps[nt][0][ln]);
    inv[1] = frcp(accS[1][0] + cps[nt][1][ln]);
    #pragma unroll
    for (int ct=0; ct<2; ct++){
      #pragma unroll
      for (int j=0;j<2;j++){
        f32x4 o = acc[ct][j] + *(const f32x4*)&cmb[nt][lane][(ct*2+j)*4];
        unsigned lo = cvtpk(o[0]*inv[j], o[1]*inv[j]);
        unsigned hi = cvtpk(o[2]*inv[j], o[3]*inv[j]);
        unsigned long long pk = ((unsigned long long)hi<<32) | lo;
        *(unsigned long long*)&OT[(size_t)(nbase+16*j+ln)*128 + h*32 + 16*ct + 4*g] = pk;
      }
    }
  }
}

extern "C" void kernel_launch(void* const* d_in, const int* in_sizes, int n_in,
                              void* d_out, int out_size, void* d_ws, size_t ws_size,
                              hipStream_t stream)
{
  const float* feat1 = (const float*)d_in[0];
  const float* feat2 = (const float*)d_in[1];
  const float* Wq = (const float*)d_in[2];  const float* bq = (const float*)d_in[3];
  const float* Wk = (const float*)d_in[4];  const float* bk = (const float*)d_in[5];
  const float* Wv = (const float*)d_in[6];  const float* bv = (const float*)d_in[7];
  const float* Wo = (const float*)d_in[8];  const float* bo = (const float*)d_in[9];
  const float* Wg1 = (const float*)d_in[10]; const float* bg1 = (const float*)d_in[11];
  const float* Wg2 = (const float*)d_in[12]; const float* bg2 = (const float*)d_in[13];

  __hip_bfloat16* WQb  = (__hip_bfloat16*)d_ws;
  __hip_bfloat16* WKb  = WQb + 16384;
  __hip_bfloat16* WVb  = WQb + 32768;
  __hip_bfloat16* WOb  = WQb + 49152;
  __hip_bfloat16* WG1b = WQb + 65536;
  __hip_bfloat16* WG2b = WQb + 98304;
  __hip_bfloat16* F1T  = WQb + 114688;
  __hip_bfloat16* F2T  = F1T + 1048576;
  __hip_bfloat16* QT   = F1T + 2*1048576;
  __hip_bfloat16* KT   = F1T + 3*1048576;
  __hip_bfloat16* Vbf  = F1T + 4*1048576;
  __hip_bfloat16* OT   = F1T + 5*1048576;
  __hip_bfloat16* AOT  = F1T + 6*1048576;
  __hip_bfloat16* G1T  = F1T + 7*1048576;

  wprep<<<448,256,0,stream>>>(Wq,Wk,Wv,Wo,Wg1,Wg2,WQb);
  transpose2<<<dim3(128,2),256,0,stream>>>(feat1, feat2, F1T, F2T);
  qkv<<<dim3(512,3),256,0,stream>>>(F1T,F2T,WQb,bq,bk,bv,QT,KT,Vbf);
  attn8<<<dim3(128,4),256,0,stream>>>(QT,KT,Vbf,OT);
  gemmT<4,4><<<512,256,0,stream>>>(OT ,OT ,WOb ,128,bo ,1.f, AOT,0,nullptr,nullptr,nullptr);
  gemmT<8,4><<<512,256,0,stream>>>(AOT,F1T,WG1b,256,bg1,1.f, G1T,2,nullptr,nullptr,nullptr);
  gemmT<4,4><<<512,256,0,stream>>>(G1T,G1T,WG2b,128,bg2,1.f, nullptr,3,feat1,AOT,(float*)d_out);
}

// Round 8
// 100.929 us; speedup vs baseline: 1.1715x; 1.0353x over previous
//
#include <hip/hip_runtime.h>
#include <hip/hip_bf16.h>

// I2I CrossAttention + gate fusion, MI355X (gfx950).
// B=1, C=128, D*H*W = N = 8192, HEADS=4, DH=32.
// Round 8: attn cross-step pipeline (T15): per step issue QK(t) + PV(t-1) +
//          accS(t-1) as one MFMA cluster, then exp(t)/cvtpk(t) on VALU —
//          breaks the serial ds->QK->exp->PV chain. 4 rotating stage buffers
//          so V(t-1) stays readable; pb double-buffered in regs via parity
//          unroll. Schedule (vmcnt(4)+barrier) and all math identical to R7.

typedef __attribute__((ext_vector_type(4))) float f32x4;
typedef __attribute__((ext_vector_type(4))) unsigned u32x4;
typedef __attribute__((ext_vector_type(8))) short s16x8;
typedef __attribute__((ext_vector_type(4))) short s16x4;

#define MFMA_BF16(A,B,C) __builtin_amdgcn_mfma_f32_16x16x32_bf16((A),(B),(C),0,0,0)

static __device__ __forceinline__ float fexp2(float x){
  float r; asm("v_exp_f32 %0, %1" : "=v"(r) : "v"(x)); return r;
}
static __device__ __forceinline__ float frcp(float x){
  float r; asm("v_rcp_f32 %0, %1" : "=v"(r) : "v"(x)); return r;
}
static __device__ __forceinline__ unsigned cvtpk(float lo, float hi){
  unsigned r; asm("v_cvt_pk_bf16_f32 %0, %1, %2" : "=v"(r) : "v"(lo), "v"(hi)); return r;
}

__device__ __forceinline__ void gll16(const void* g, void* l){
  __builtin_amdgcn_global_load_lds(
      (const __attribute__((address_space(1))) void*)g,
      (__attribute__((address_space(3))) void*)l, 16, 0, 0);
}

// ---------------- weight prep: fp32 -> bf16 (Wq scaled) ----------------
__global__ __launch_bounds__(256) void wprep(
    const float* __restrict__ Wq, const float* __restrict__ Wk,
    const float* __restrict__ Wv, const float* __restrict__ Wo,
    const float* __restrict__ Wg1, const float* __restrict__ Wg2,
    __hip_bfloat16* __restrict__ out)
{
  int i = blockIdx.x*256 + threadIdx.x;              // 0..114687
  const float SCQ = 0.17677669529663689f * 1.44269504088896340f;
  float v;
  if      (i < 16384) v = Wq[i]*SCQ;
  else if (i < 32768) v = Wk[i-16384];
  else if (i < 49152) v = Wv[i-32768];
  else if (i < 65536) v = Wo[i-49152];
  else if (i < 98304) v = Wg1[i-65536];
  else                v = Wg2[i-98304];
  out[i] = __float2bfloat16(v);
}

// ------- transpose [128][8192] fp32 -> [8192][128] bf16 (y: feat1/feat2) -------
__global__ __launch_bounds__(256) void transpose2(
    const float* __restrict__ f1, const float* __restrict__ f2,
    __hip_bfloat16* __restrict__ F1T, __hip_bfloat16* __restrict__ F2T)
{
  const float* in = blockIdx.y ? f2 : f1;
  __hip_bfloat16* out = blockIdx.y ? F2T : F1T;
  __shared__ __hip_bfloat16 tile[64][128];
  int tid = threadIdx.x;
  int n0 = blockIdx.x*64;
  int cq = tid>>4;
  int nq = (tid&15)*4;
  #pragma unroll
  for (int r=0;r<8;r++){
    int c = r*16 + cq;
    f32x4 val = *(const f32x4*)&in[c*8192 + n0 + nq];
    #pragma unroll
    for (int i=0;i<4;i++){
      int n = nq + i;
      tile[n][c ^ ((n&7)<<4)] = __float2bfloat16(val[i]);
    }
  }
  __syncthreads();
  int row = tid>>2;
  int cb  = (tid&3)*32;
  #pragma unroll
  for (int k=0;k<4;k++){
    int c0 = cb + 8*k;
    s16x8 v = *(const s16x8*)&tile[row][c0 ^ ((row&7)<<4)];
    *(s16x8*)&out[(n0+row)*128 + c0] = v;
  }
}

// ---------------- fused Q/K/V projection (blockIdx.y selects) ----------------
__global__ __launch_bounds__(256) void qkv(
    const __hip_bfloat16* __restrict__ F1T, const __hip_bfloat16* __restrict__ F2T,
    const __hip_bfloat16* __restrict__ Wall,
    const float* __restrict__ bq, const float* __restrict__ bk,
    const float* __restrict__ bv,
    __hip_bfloat16* __restrict__ QT, __hip_bfloat16* __restrict__ KT,
    __hip_bfloat16* __restrict__ Vp)
{
  const float SCQ = 0.17677669529663689f * 1.44269504088896340f;
  int y = blockIdx.y;
  const __hip_bfloat16* A  = (y==0) ? F1T : F2T;
  const __hip_bfloat16* Bw = Wall + y*16384;
  const float* bias = (y==0) ? bq : (y==1) ? bk : bv;
  float bscale = (y==0) ? SCQ : 1.f;

  int tid = threadIdx.x;
  int w = tid>>6, lane = tid&63, g = lane>>4, ln = lane&15;
  int n0 = blockIdx.x*16, o0 = w*32;
  f32x4 acc0 = {0.f,0.f,0.f,0.f}, acc1 = {0.f,0.f,0.f,0.f};
  #pragma unroll
  for (int ck=0; ck<4; ck++){
    s16x8 af  = *(const s16x8*)&A[(n0+ln)*128 + ck*32 + 8*g];
    s16x8 bf0 = *(const s16x8*)&Bw[(o0+ln)*128 + ck*32 + 8*g];
    s16x8 bf1 = *(const s16x8*)&Bw[(o0+16+ln)*128 + ck*32 + 8*g];
    if (y == 2){
      acc0 = MFMA_BF16(bf0, af, acc0);
      acc1 = MFMA_BF16(bf1, af, acc1);
    } else {
      acc0 = MFMA_BF16(af, bf0, acc0);
      acc1 = MFMA_BF16(af, bf1, acc1);
    }
  }
  if (y == 2){
    // R4-validated permute: granule Gx = (4*(m63>>5) | q) ^ (o&7), pos hb*4+i
    #pragma unroll
    for (int to=0; to<2; to++){
      f32x4 a = to ? acc1 : acc0;
      #pragma unroll
      for (int r=0;r<4;r++){
        int o = o0 + 16*to + 4*g + r;
        int n = n0 + ln;
        int m63 = n & 63, blk = n >> 6;
        int Gx = (((m63>>5)<<2) | ((m63>>2)&3)) ^ (o & 7);
        int col = blk*64 + Gx*8 + ((m63>>4)&1)*4 + (m63&3);
        Vp[(size_t)o*8192 + col] = __float2bfloat16(a[r] + bias[o]);
      }
    }
  } else {
    __hip_bfloat16* outb = (y==0) ? QT : KT;
    float b0 = bias[o0+ln]*bscale, b1 = bias[o0+16+ln]*bscale;
    #pragma unroll
    for (int to=0; to<2; to++){
      f32x4 a = to ? acc1 : acc0;
      float bb = to ? b1 : b0;
      int o = o0 + 16*to + ln;
      #pragma unroll
      for (int r=0;r<4;r++){
        int n = n0 + 4*g + r;
        outb[n*128 + o] = __float2bfloat16(a[r] + bb);
      }
    }
  }
}

// ---------------- generic transposed-output channel-mix GEMM ----------------
// ep: 0 = bf16 [n][128]; 2 = relu bf16 [n][128];
//     3 = sigmoid gate fused combine -> fp32 out [c][n]
template<int KCH, int SPLIT>
__global__ __launch_bounds__(256) void gemmT(
    const __hip_bfloat16* __restrict__ A1, const __hip_bfloat16* __restrict__ A2,
    const __hip_bfloat16* __restrict__ Bw, const int bstride,
    const float* __restrict__ bias, const float bscale,
    __hip_bfloat16* __restrict__ outb, const int ep,
    const float* __restrict__ xf1, const __hip_bfloat16* __restrict__ xao,
    float* __restrict__ xout)
{
  int tid = threadIdx.x;
  int w = tid>>6, lane = tid&63, g = lane>>4, ln = lane&15;
  int n0 = blockIdx.x*16, o0 = w*32;
  f32x4 acc0 = {0.f,0.f,0.f,0.f}, acc1 = {0.f,0.f,0.f,0.f};
  #pragma unroll
  for (int ck=0; ck<KCH; ck++){
    const __hip_bfloat16* As = (ck < SPLIT) ? A1 : A2;
    int cb = ((ck < SPLIT) ? ck : (ck-SPLIT))*32;
    s16x8 af  = *(const s16x8*)&As[(n0+ln)*128 + cb + 8*g];
    s16x8 bf0 = *(const s16x8*)&Bw[(o0+ln)*bstride + ck*32 + 8*g];
    s16x8 bf1 = *(const s16x8*)&Bw[(o0+16+ln)*bstride + ck*32 + 8*g];
    acc0 = MFMA_BF16(af, bf0, acc0);
    acc1 = MFMA_BF16(af, bf1, acc1);
  }
  float b0 = bias[o0+ln]*bscale, b1 = bias[o0+16+ln]*bscale;
  #pragma unroll
  for (int to=0; to<2; to++){
    f32x4 a = to ? acc1 : acc0;
    float bb = to ? b1 : b0;
    int o = o0 + 16*to + ln;
    #pragma unroll
    for (int r=0;r<4;r++){
      int n = n0 + 4*g + r;
      float v = a[r] + bb;
      if (ep == 2) v = fmaxf(v, 0.f);
      if (ep == 3){
        float gt = frcp(1.f + fexp2(-1.44269504f*v));
        float f1 = xf1[(size_t)o*8192 + n];
        float ao = __bfloat162float(xao[n*128 + o]);
        xout[(size_t)o*8192 + n] = gt*f1 + (1.f - gt)*ao;
      } else {
        outb[n*128 + o] = __float2bfloat16(v);
      }
    }
  }
}

// ---------------- fused attention: cross-step pipelined (T15) ----------------
// Block: 256 threads = 4 waves; wave w: nt = w&1 (32-n tile), mh = w>>1 (m-half).
// Grid (128,4) = 512 blocks (2/CU). 4 x 16KB rotating stage buffers, loads 2
// steps in flight. Per step t: [QK(t) | PV(t-1) | accS(t-1)] MFMA cluster, then
// exp(t)/cvtpk(t). pb double-buffered via parity-unrolled loop.
__global__ __launch_bounds__(256, 2) void attn9(
    const __hip_bfloat16* __restrict__ QT, const __hip_bfloat16* __restrict__ KT,
    const __hip_bfloat16* __restrict__ Vp, __hip_bfloat16* __restrict__ OT)
{
  __shared__ short stage[4][8192];     // [buf][16KB]: K0 V0 K1 V1 (4KB each)
  __shared__ float cmb[2][64][16];     // mh=1 partial accs
  __shared__ float cps[2][2][16];      // mh=1 partial psums

  const int tid = threadIdx.x;
  const int w = tid>>6, lane = tid&63, g = lane>>4, ln = lane&15;
  const int nt = w&1, mh = w>>1;
  const int h = blockIdx.y;
  const int nbase = blockIdx.x*64 + nt*32;

  const __hip_bfloat16* Kh = KT + h*32;
  const __hip_bfloat16* Vh = Vp + (size_t)(h*32)*8192;

  // Q fragments (Q pre-scaled by SCALE*log2e)
  s16x8 qf[2];
  qf[0] = *(const s16x8*)&QT[(size_t)(nbase+ln)*128 + h*32 + 8*g];
  qf[1] = *(const s16x8*)&QT[(size_t)(nbase+16+ln)*128 + h*32 + 8*g];

  // ---- staging sources: thread covers segments 4w..4w+3 (16 x 1KB) ----
  const __hip_bfloat16* gp[4];
  int gstep[4], ldoff[4];
  #pragma unroll
  for (int u=0; u<4; u++){
    int seg = 4*w + u;
    int smh = seg>>3, rem = seg&7, isV = rem>>2, sr = rem&3;
    if (!isV){
      int row = sr*16 + (lane>>2);
      int gk  = (lane&3) ^ ((lane>>3)&3);             // source-side K swizzle
      gp[u] = &Kh[(size_t)(smh*4096 + row)*128 + 8*gk];
      gstep[u] = 64*128;
    } else {
      int c = sr*8 + (lane>>3);                        // linear V copy
      gp[u] = &Vh[(size_t)c*8192 + smh*4096 + 8*(lane&7)];
      gstep[u] = 64;
    }
    ldoff[u] = seg*512;                                // shorts (1 KB per seg)
  }
  short* sb = &stage[0][0];

  #define ISSUE(OFF) { \
    _Pragma("unroll") \
    for (int u=0;u<4;u++){ gll16(gp[u], sb + (OFF) + ldoff[u]); gp[u] += gstep[u]; } }

  // ---- LDS read offsets (shorts) ----
  const int kloff = ln*32 + ((g ^ ((ln>>1)&3))<<3);    // + r*512, within K half
  int voff[2];                                         // [kk], + (16ct+ln)*64
  voff[0] = 8*((g  ) ^ (ln&7));
  voff[1] = 8*((g+4) ^ (ln&7));

  const u32x4 onesw = {0x3F803F80u,0x3F803F80u,0x3F803F80u,0x3F803F80u};
  const s16x8 onesf = __builtin_bit_cast(s16x8, onesw);

  f32x4 acc[2][2];                                     // [ct][j]
  #pragma unroll
  for (int t=0;t<2;t++){ acc[t][0]=(f32x4){0,0,0,0}; acc[t][1]=(f32x4){0,0,0,0}; }
  f32x4 accS[2] = {(f32x4){0,0,0,0},(f32x4){0,0,0,0}};  // ones-MFMA psum
  s16x8 pbA[2][2], pbB[2][2];                           // [kk][j]

  // prologue: stage steps 0,1 into bufs 0,1 (8 loads in flight per thread)
  ISSUE(0);
  ISSUE(8192);

  unsigned roff = 0, ioff = 16384;

  // one pipeline step: MFMA cluster = QK(t) + PV(t-1 via PBIN) + accS(t-1);
  // then exp(t)/cvtpk(t) -> PBOUT. ISSUE(t+2) into buf[(t+2)&3] (read at t-2/t-1).
  #define STEP(PBIN, PBOUT, DO_PV) { \
    asm volatile("s_waitcnt vmcnt(4)" ::: "memory"); \
    __builtin_amdgcn_s_barrier(); \
    ISSUE(ioff); ioff = (ioff + 8192u) & 32767u; \
    const short* Kl = sb + roff + mh*4096; \
    const short* Vq = sb + ((roff + 24576u) & 32767u) + mh*4096 + 2048; \
    roff = (roff + 8192u) & 32767u; \
    s16x8 kf0 = *(const s16x8*)&Kl[         kloff]; \
    s16x8 kf1 = *(const s16x8*)&Kl[ 512  +  kloff]; \
    s16x8 kf2 = *(const s16x8*)&Kl[1024  +  kloff]; \
    s16x8 kf3 = *(const s16x8*)&Kl[1536  +  kloff]; \
    s16x8 vf00, vf01, vf10, vf11; \
    if (DO_PV){ \
      vf00 = *(const s16x8*)&Vq[(   ln)*64 + voff[0]]; \
      vf01 = *(const s16x8*)&Vq[(16+ln)*64 + voff[0]]; \
      vf10 = *(const s16x8*)&Vq[(   ln)*64 + voff[1]]; \
      vf11 = *(const s16x8*)&Vq[(16+ln)*64 + voff[1]]; \
    } \
    f32x4 z = {0.f,0.f,0.f,0.f}; \
    __builtin_amdgcn_s_setprio(1); \
    f32x4 s00 = MFMA_BF16(kf0, qf[0], z), s01 = MFMA_BF16(kf0, qf[1], z); \
    f32x4 s10 = MFMA_BF16(kf1, qf[0], z), s11 = MFMA_BF16(kf1, qf[1], z); \
    f32x4 s20 = MFMA_BF16(kf2, qf[0], z), s21 = MFMA_BF16(kf2, qf[1], z); \
    f32x4 s30 = MFMA_BF16(kf3, qf[0], z), s31 = MFMA_BF16(kf3, qf[1], z); \
    if (DO_PV){ \
      acc[0][0] = MFMA_BF16(vf00, PBIN[0][0], acc[0][0]); \
      acc[0][1] = MFMA_BF16(vf00, PBIN[0][1], acc[0][1]); \
      acc[1][0] = MFMA_BF16(vf01, PBIN[0][0], acc[1][0]); \
      acc[1][1] = MFMA_BF16(vf01, PBIN[0][1], acc[1][1]); \
      acc[0][0] = MFMA_BF16(vf10, PBIN[1][0], acc[0][0]); \
      acc[0][1] = MFMA_BF16(vf10, PBIN[1][1], acc[0][1]); \
      acc[1][0] = MFMA_BF16(vf11, PBIN[1][0], acc[1][0]); \
      acc[1][1] = MFMA_BF16(vf11, PBIN[1][1], acc[1][1]); \
      accS[0] = MFMA_BF16(onesf, PBIN[0][0], accS[0]); \
      accS[1] = MFMA_BF16(onesf, PBIN[0][1], accS[1]); \
      accS[0] = MFMA_BF16(onesf, PBIN[1][0], accS[0]); \
      accS[1] = MFMA_BF16(onesf, PBIN[1][1], accS[1]); \
    } \
    __builtin_amdgcn_s_setprio(0); \
    { \
      float a0,a1,a2,a3,b0,b1,b2,b3; u32x4 pw; \
      a0=fexp2(s00[0]); a1=fexp2(s00[1]); a2=fexp2(s00[2]); a3=fexp2(s00[3]); \
      b0=fexp2(s10[0]); b1=fexp2(s10[1]); b2=fexp2(s10[2]); b3=fexp2(s10[3]); \
      pw[0]=cvtpk(a0,a1); pw[1]=cvtpk(a2,a3); pw[2]=cvtpk(b0,b1); pw[3]=cvtpk(b2,b3); \
      PBOUT[0][0] = __builtin_bit_cast(s16x8, pw); \
      a0=fexp2(s01[0]); a1=fexp2(s01[1]); a2=fexp2(s01[2]); a3=fexp2(s01[3]); \
      b0=fexp2(s11[0]); b1=fexp2(s11[1]); b2=fexp2(s11[2]); b3=fexp2(s11[3]); \
      pw[0]=cvtpk(a0,a1); pw[1]=cvtpk(a2,a3); pw[2]=cvtpk(b0,b1); pw[3]=cvtpk(b2,b3); \
      PBOUT[0][1] = __builtin_bit_cast(s16x8, pw); \
      a0=fexp2(s20[0]); a1=fexp2(s20[1]); a2=fexp2(s20[2]); a3=fexp2(s20[3]); \
      b0=fexp2(s30[0]); b1=fexp2(s30[1]); b2=fexp2(s30[2]); b3=fexp2(s30[3]); \
      pw[0]=cvtpk(a0,a1); pw[1]=cvtpk(a2,a3); pw[2]=cvtpk(b0,b1); pw[3]=cvtpk(b2,b3); \
      PBOUT[1][0] = __builtin_bit_cast(s16x8, pw); \
      a0=fexp2(s21[0]); a1=fexp2(s21[1]); a2=fexp2(s21[2]); a3=fexp2(s21[3]); \
      b0=fexp2(s31[0]); b1=fexp2(s31[1]); b2=fexp2(s31[2]); b3=fexp2(s31[3]); \
      pw[0]=cvtpk(a0,a1); pw[1]=cvtpk(a2,a3); pw[2]=cvtpk(b0,b1); pw[3]=cvtpk(b2,b3); \
      PBOUT[1][1] = __builtin_bit_cast(s16x8, pw); \
    } \
  }

  // step 0: QK+exp only -> pbA
  STEP(pbA, pbA, 0);
  // steps 1..62: 31 parity pairs
  for (int it=0; it<31; ++it){
    STEP(pbA, pbB, 1);
    STEP(pbB, pbA, 1);
  }
  // step 63
  STEP(pbA, pbB, 1);
  #undef STEP
  #undef ISSUE

  // epilogue: PV(63) + accS(63) from buf3's V (written by ISSUE(63), waited at 63)
  {
    const short* Vq = sb + 24576 + mh*4096 + 2048;
    s16x8 vf00 = *(const s16x8*)&Vq[(   ln)*64 + voff[0]];
    s16x8 vf01 = *(const s16x8*)&Vq[(16+ln)*64 + voff[0]];
    s16x8 vf10 = *(const s16x8*)&Vq[(   ln)*64 + voff[1]];
    s16x8 vf11 = *(const s16x8*)&Vq[(16+ln)*64 + voff[1]];
    acc[0][0] = MFMA_BF16(vf00, pbB[0][0], acc[0][0]);
    acc[0][1] = MFMA_BF16(vf00, pbB[0][1], acc[0][1]);
    acc[1][0] = MFMA_BF16(vf01, pbB[0][0], acc[1][0]);
    acc[1][1] = MFMA_BF16(vf01, pbB[0][1], acc[1][1]);
    acc[0][0] = MFMA_BF16(vf10, pbB[1][0], acc[0][0]);
    acc[0][1] = MFMA_BF16(vf10, pbB[1][1], acc[0][1]);
    acc[1][0] = MFMA_BF16(vf11, pbB[1][0], acc[1][0]);
    acc[1][1] = MFMA_BF16(vf11, pbB[1][1], acc[1][1]);
    accS[0] = MFMA_BF16(onesf, pbB[0][0], accS[0]);
    accS[1] = MFMA_BF16(onesf, pbB[0][1], accS[1]);
    accS[0] = MFMA_BF16(onesf, pbB[1][0], accS[0]);
    accS[1] = MFMA_BF16(onesf, pbB[1][1], accS[1]);
  }

  // ---- combine m-halves; accS[j][0] == psum for n = nbase+16j+ln (all lanes)
  if (mh == 1){
    #pragma unroll
    for (int ct=0; ct<2; ct++)
      #pragma unroll
      for (int j=0;j<2;j++)
        *(f32x4*)&cmb[nt][lane][(ct*2+j)*4] = acc[ct][j];
    if (lane < 16){ cps[nt][0][lane] = accS[0][0]; cps[nt][1][lane] = accS[1][0]; }
  }
  __syncthreads();
  if (mh == 0){
    float inv[2];
    inv[0] = frcp(accS[0][0] + cps[nt][0][ln]);
    inv[1] = frcp(accS[1][0] + cps[nt][1][ln]);
    #pragma unroll
    for (int ct=0; ct<2; ct++){
      #pragma unroll
      for (int j=0;j<2;j++){
        f32x4 o = acc[ct][j] + *(const f32x4*)&cmb[nt][lane][(ct*2+j)*4];
        unsigned lo = cvtpk(o[0]*inv[j], o[1]*inv[j]);
        unsigned hi = cvtpk(o[2]*inv[j], o[3]*inv[j]);
        unsigned long long pk = ((unsigned long long)hi<<32) | lo;
        *(unsigned long long*)&OT[(size_t)(nbase+16*j+ln)*128 + h*32 + 16*ct + 4*g] = pk;
      }
    }
  }
}

extern "C" void kernel_launch(void* const* d_in, const int* in_sizes, int n_in,
                              void* d_out, int out_size, void* d_ws, size_t ws_size,
                              hipStream_t stream)
{
  const float* feat1 = (const float*)d_in[0];
  const float* feat2 = (const float*)d_in[1];
  const float* Wq = (const float*)d_in[2];  const float* bq = (const float*)d_in[3];
  const float* Wk = (const float*)d_in[4];  const float* bk = (const float*)d_in[5];
  const float* Wv = (const float*)d_in[6];  const float* bv = (const float*)d_in[7];
  const float* Wo = (const float*)d_in[8];  const float* bo = (const float*)d_in[9];
  const float* Wg1 = (const float*)d_in[10]; const float* bg1 = (const float*)d_in[11];
  const float* Wg2 = (const float*)d_in[12]; const float* bg2 = (const float*)d_in[13];

  __hip_bfloat16* WQb  = (__hip_bfloat16*)d_ws;
  __hip_bfloat16* WKb  = WQb + 16384;
  __hip_bfloat16* WVb  = WQb + 32768;
  __hip_bfloat16* WOb  = WQb + 49152;
  __hip_bfloat16* WG1b = WQb + 65536;
  __hip_bfloat16* WG2b = WQb + 98304;
  __hip_bfloat16* F1T  = WQb + 114688;
  __hip_bfloat16* F2T  = F1T + 1048576;
  __hip_bfloat16* QT   = F1T + 2*1048576;
  __hip_bfloat16* KT   = F1T + 3*1048576;
  __hip_bfloat16* Vbf  = F1T + 4*1048576;
  __hip_bfloat16* OT   = F1T + 5*1048576;
  __hip_bfloat16* AOT  = F1T + 6*1048576;
  __hip_bfloat16* G1T  = F1T + 7*1048576;

  wprep<<<448,256,0,stream>>>(Wq,Wk,Wv,Wo,Wg1,Wg2,WQb);
  transpose2<<<dim3(128,2),256,0,stream>>>(feat1, feat2, F1T, F2T);
  qkv<<<dim3(512,3),256,0,stream>>>(F1T,F2T,WQb,bq,bk,bv,QT,KT,Vbf);
  attn9<<<dim3(128,4),256,0,stream>>>(QT,KT,Vbf,OT);
  gemmT<4,4><<<512,256,0,stream>>>(OT ,OT ,WOb ,128,bo ,1.f, AOT,0,nullptr,nullptr,nullptr);
  gemmT<8,4><<<512,256,0,stream>>>(AOT,F1T,WG1b,256,bg1,1.f, G1T,2,nullptr,nullptr,nullptr);
  gemmT<4,4><<<512,256,0,stream>>>(G1T,G1T,WG2b,128,bg2,1.f, nullptr,3,feat1,AOT,(float*)d_out);
}

// Round 9
// 95.505 us; speedup vs baseline: 1.2380x; 1.0568x over previous
//
#include <hip/hip_runtime.h>
#include <hip/hip_bf16.h>

// I2I CrossAttention + gate fusion, MI355X (gfx950).
// B=1, C=128, D*H*W = N = 8192, HEADS=4, DH=32.
// Round 9: attn work-rebalance — wave = 64n x 64m per step (2x useful work at
//          ~same per-step overhead). Block = 4 waves = 4 m-quarters over one
//          64-n tile; grid (128,4) = 2 blocks/CU. Depth-1 dbuf schedule (R4),
//          per-64-m staging/LDS patterns verbatim from R7. psum on VALU
//          (drops ones-MFMA, 20% of matrix pipe). 4-way combine via
//          stage-scratch reuse after vmcnt(0)+syncthreads.

typedef __attribute__((ext_vector_type(4))) float f32x4;
typedef __attribute__((ext_vector_type(4))) unsigned u32x4;
typedef __attribute__((ext_vector_type(8))) short s16x8;
typedef __attribute__((ext_vector_type(4))) short s16x4;

#define MFMA_BF16(A,B,C) __builtin_amdgcn_mfma_f32_16x16x32_bf16((A),(B),(C),0,0,0)

static __device__ __forceinline__ float fexp2(float x){
  float r; asm("v_exp_f32 %0, %1" : "=v"(r) : "v"(x)); return r;
}
static __device__ __forceinline__ float frcp(float x){
  float r; asm("v_rcp_f32 %0, %1" : "=v"(r) : "v"(x)); return r;
}
static __device__ __forceinline__ unsigned cvtpk(float lo, float hi){
  unsigned r; asm("v_cvt_pk_bf16_f32 %0, %1, %2" : "=v"(r) : "v"(lo), "v"(hi)); return r;
}

__device__ __forceinline__ void gll16(const void* g, void* l){
  __builtin_amdgcn_global_load_lds(
      (const __attribute__((address_space(1))) void*)g,
      (__attribute__((address_space(3))) void*)l, 16, 0, 0);
}

// ---------------- weight prep: fp32 -> bf16 (Wq scaled) ----------------
__global__ __launch_bounds__(256) void wprep(
    const float* __restrict__ Wq, const float* __restrict__ Wk,
    const float* __restrict__ Wv, const float* __restrict__ Wo,
    const float* __restrict__ Wg1, const float* __restrict__ Wg2,
    __hip_bfloat16* __restrict__ out)
{
  int i = blockIdx.x*256 + threadIdx.x;              // 0..114687
  const float SCQ = 0.17677669529663689f * 1.44269504088896340f;
  float v;
  if      (i < 16384) v = Wq[i]*SCQ;
  else if (i < 32768) v = Wk[i-16384];
  else if (i < 49152) v = Wv[i-32768];
  else if (i < 65536) v = Wo[i-49152];
  else if (i < 98304) v = Wg1[i-65536];
  else                v = Wg2[i-98304];
  out[i] = __float2bfloat16(v);
}

// ------- transpose [128][8192] fp32 -> [8192][128] bf16 (y: feat1/feat2) -------
__global__ __launch_bounds__(256) void transpose2(
    const float* __restrict__ f1, const float* __restrict__ f2,
    __hip_bfloat16* __restrict__ F1T, __hip_bfloat16* __restrict__ F2T)
{
  const float* in = blockIdx.y ? f2 : f1;
  __hip_bfloat16* out = blockIdx.y ? F2T : F1T;
  __shared__ __hip_bfloat16 tile[64][128];
  int tid = threadIdx.x;
  int n0 = blockIdx.x*64;
  int cq = tid>>4;
  int nq = (tid&15)*4;
  #pragma unroll
  for (int r=0;r<8;r++){
    int c = r*16 + cq;
    f32x4 val = *(const f32x4*)&in[c*8192 + n0 + nq];
    #pragma unroll
    for (int i=0;i<4;i++){
      int n = nq + i;
      tile[n][c ^ ((n&7)<<4)] = __float2bfloat16(val[i]);
    }
  }
  __syncthreads();
  int row = tid>>2;
  int cb  = (tid&3)*32;
  #pragma unroll
  for (int k=0;k<4;k++){
    int c0 = cb + 8*k;
    s16x8 v = *(const s16x8*)&tile[row][c0 ^ ((row&7)<<4)];
    *(s16x8*)&out[(n0+row)*128 + c0] = v;
  }
}

// ---------------- fused Q/K/V projection (blockIdx.y selects) ----------------
__global__ __launch_bounds__(256) void qkv(
    const __hip_bfloat16* __restrict__ F1T, const __hip_bfloat16* __restrict__ F2T,
    const __hip_bfloat16* __restrict__ Wall,
    const float* __restrict__ bq, const float* __restrict__ bk,
    const float* __restrict__ bv,
    __hip_bfloat16* __restrict__ QT, __hip_bfloat16* __restrict__ KT,
    __hip_bfloat16* __restrict__ Vp)
{
  const float SCQ = 0.17677669529663689f * 1.44269504088896340f;
  int y = blockIdx.y;
  const __hip_bfloat16* A  = (y==0) ? F1T : F2T;
  const __hip_bfloat16* Bw = Wall + y*16384;
  const float* bias = (y==0) ? bq : (y==1) ? bk : bv;
  float bscale = (y==0) ? SCQ : 1.f;

  int tid = threadIdx.x;
  int w = tid>>6, lane = tid&63, g = lane>>4, ln = lane&15;
  int n0 = blockIdx.x*16, o0 = w*32;
  f32x4 acc0 = {0.f,0.f,0.f,0.f}, acc1 = {0.f,0.f,0.f,0.f};
  #pragma unroll
  for (int ck=0; ck<4; ck++){
    s16x8 af  = *(const s16x8*)&A[(n0+ln)*128 + ck*32 + 8*g];
    s16x8 bf0 = *(const s16x8*)&Bw[(o0+ln)*128 + ck*32 + 8*g];
    s16x8 bf1 = *(const s16x8*)&Bw[(o0+16+ln)*128 + ck*32 + 8*g];
    if (y == 2){
      acc0 = MFMA_BF16(bf0, af, acc0);
      acc1 = MFMA_BF16(bf1, af, acc1);
    } else {
      acc0 = MFMA_BF16(af, bf0, acc0);
      acc1 = MFMA_BF16(af, bf1, acc1);
    }
  }
  if (y == 2){
    // R4-validated permute: granule Gx = (4*(m63>>5) | q) ^ (o&7), pos hb*4+i
    #pragma unroll
    for (int to=0; to<2; to++){
      f32x4 a = to ? acc1 : acc0;
      #pragma unroll
      for (int r=0;r<4;r++){
        int o = o0 + 16*to + 4*g + r;
        int n = n0 + ln;
        int m63 = n & 63, blk = n >> 6;
        int Gx = (((m63>>5)<<2) | ((m63>>2)&3)) ^ (o & 7);
        int col = blk*64 + Gx*8 + ((m63>>4)&1)*4 + (m63&3);
        Vp[(size_t)o*8192 + col] = __float2bfloat16(a[r] + bias[o]);
      }
    }
  } else {
    __hip_bfloat16* outb = (y==0) ? QT : KT;
    float b0 = bias[o0+ln]*bscale, b1 = bias[o0+16+ln]*bscale;
    #pragma unroll
    for (int to=0; to<2; to++){
      f32x4 a = to ? acc1 : acc0;
      float bb = to ? b1 : b0;
      int o = o0 + 16*to + ln;
      #pragma unroll
      for (int r=0;r<4;r++){
        int n = n0 + 4*g + r;
        outb[n*128 + o] = __float2bfloat16(a[r] + bb);
      }
    }
  }
}

// ---------------- generic transposed-output channel-mix GEMM ----------------
// ep: 0 = bf16 [n][128]; 2 = relu bf16 [n][128];
//     3 = sigmoid gate fused combine -> fp32 out [c][n]
template<int KCH, int SPLIT>
__global__ __launch_bounds__(256) void gemmT(
    const __hip_bfloat16* __restrict__ A1, const __hip_bfloat16* __restrict__ A2,
    const __hip_bfloat16* __restrict__ Bw, const int bstride,
    const float* __restrict__ bias, const float bscale,
    __hip_bfloat16* __restrict__ outb, const int ep,
    const float* __restrict__ xf1, const __hip_bfloat16* __restrict__ xao,
    float* __restrict__ xout)
{
  int tid = threadIdx.x;
  int w = tid>>6, lane = tid&63, g = lane>>4, ln = lane&15;
  int n0 = blockIdx.x*16, o0 = w*32;
  f32x4 acc0 = {0.f,0.f,0.f,0.f}, acc1 = {0.f,0.f,0.f,0.f};
  #pragma unroll
  for (int ck=0; ck<KCH; ck++){
    const __hip_bfloat16* As = (ck < SPLIT) ? A1 : A2;
    int cb = ((ck < SPLIT) ? ck : (ck-SPLIT))*32;
    s16x8 af  = *(const s16x8*)&As[(n0+ln)*128 + cb + 8*g];
    s16x8 bf0 = *(const s16x8*)&Bw[(o0+ln)*bstride + ck*32 + 8*g];
    s16x8 bf1 = *(const s16x8*)&Bw[(o0+16+ln)*bstride + ck*32 + 8*g];
    acc0 = MFMA_BF16(af, bf0, acc0);
    acc1 = MFMA_BF16(af, bf1, acc1);
  }
  float b0 = bias[o0+ln]*bscale, b1 = bias[o0+16+ln]*bscale;
  #pragma unroll
  for (int to=0; to<2; to++){
    f32x4 a = to ? acc1 : acc0;
    float bb = to ? b1 : b0;
    int o = o0 + 16*to + ln;
    #pragma unroll
    for (int r=0;r<4;r++){
      int n = n0 + 4*g + r;
      float v = a[r] + bb;
      if (ep == 2) v = fmaxf(v, 0.f);
      if (ep == 3){
        float gt = frcp(1.f + fexp2(-1.44269504f*v));
        float f1 = xf1[(size_t)o*8192 + n];
        float ao = __bfloat162float(xao[n*128 + o]);
        xout[(size_t)o*8192 + n] = gt*f1 + (1.f - gt)*ao;
      } else {
        outb[n*128 + o] = __float2bfloat16(v);
      }
    }
  }
}

// ---------------- fused attention: 64n x 64m wave-steps, 4 m-quarters ----------------
// Block: 256 threads = 4 waves; wave w = m-quarter (2048 m each), all waves
// share one 64-n tile. Grid (128,4) = 512 blocks (2/CU). 32 steps; per step
// each wave: 64 m x 64 n. 2 x 32KB stage dbuf (depth-1, R4 schedule); combine
// via stage-scratch reuse.
__global__ __launch_bounds__(256, 2) void attn10(
    const __hip_bfloat16* __restrict__ QT, const __hip_bfloat16* __restrict__ KT,
    const __hip_bfloat16* __restrict__ Vp, __hip_bfloat16* __restrict__ OT)
{
  __shared__ short stage[2][16384];   // 2 x 32KB: quarter q at q*4096: K(2K sh) V(2K sh)

  const int tid = threadIdx.x;
  const int w = tid>>6, lane = tid&63, g = lane>>4, ln = lane&15;
  const int h = blockIdx.y;
  const int nbase = blockIdx.x*64;

  const __hip_bfloat16* Kh = KT + h*32;
  const __hip_bfloat16* Vh = Vp + (size_t)(h*32)*8192;

  // Q fragments (Q pre-scaled by SCALE*log2e): 64 n per wave
  s16x8 qf[4];
  #pragma unroll
  for (int j=0;j<4;j++)
    qf[j] = *(const s16x8*)&QT[(size_t)(nbase+16*j+ln)*128 + h*32 + 8*g];

  // ---- staging: wave w stages its own quarter (8 segs x 1KB per step) ----
  // segs 0-3: K rows (within 64-m tile), R7 source chunk-swizzle;
  // segs 4-7: V c-rows, linear copy (Vp pre-permuted + bank-XORed).
  const __hip_bfloat16* gp[8];
  int gstep[8], ldoff[8];
  #pragma unroll
  for (int u=0; u<8; u++){
    if (u < 4){
      int row = u*16 + (lane>>2);
      int gk  = (lane&3) ^ ((lane>>3)&3);             // source-side K swizzle
      gp[u] = &Kh[(size_t)(w*2048 + row)*128 + 8*gk];
      gstep[u] = 64*128;
      ldoff[u] = w*4096 + u*512;
    } else {
      int c = (u-4)*8 + (lane>>3);                     // linear V copy
      gp[u] = &Vh[(size_t)c*8192 + w*2048 + 8*(lane&7)];
      gstep[u] = 64;
      ldoff[u] = w*4096 + 2048 + (u-4)*512;
    }
  }
  short* sb = &stage[0][0];

  #define ISSUE(OFF) { \
    _Pragma("unroll") \
    for (int u=0;u<8;u++){ gll16(gp[u], sb + (OFF) + ldoff[u]); gp[u] += gstep[u]; } }

  // ---- LDS read offsets (shorts), verbatim R7 formulas ----
  const int kloff = ln*32 + ((g ^ ((ln>>1)&3))<<3);    // + r*512, within K region
  int voff[2];                                         // [kk], + (16ct+ln)*64
  voff[0] = 8*((g  ) ^ (ln&7));
  voff[1] = 8*((g+4) ^ (ln&7));

  f32x4 acc[2][4];                                     // [ct][j]
  #pragma unroll
  for (int ct=0;ct<2;ct++)
    #pragma unroll
    for (int j=0;j<4;j++) acc[ct][j] = (f32x4){0.f,0.f,0.f,0.f};
  float psum[4] = {0.f,0.f,0.f,0.f};

  ISSUE(0);                                            // prologue: step 0
  for (int t=0; t<32; ++t){
    asm volatile("s_waitcnt vmcnt(0)" ::: "memory");   // my 8 loads done
    __builtin_amdgcn_s_barrier();                      // => all waves' loads done
    const int cur = (t&1)<<14;
    ISSUE(16384 - cur);                                // prefetch t+1 (depth-1)

    const short* Kl = sb + cur + w*4096;
    const short* Vl = Kl + 2048;

    // K + V fragments (V early: LDS latency hides under QK MFMAs)
    s16x8 kf0 = *(const s16x8*)&Kl[         kloff];
    s16x8 kf1 = *(const s16x8*)&Kl[ 512  +  kloff];
    s16x8 kf2 = *(const s16x8*)&Kl[1024  +  kloff];
    s16x8 kf3 = *(const s16x8*)&Kl[1536  +  kloff];
    s16x8 vf00 = *(const s16x8*)&Vl[(   ln)*64 + voff[0]];
    s16x8 vf01 = *(const s16x8*)&Vl[(16+ln)*64 + voff[0]];
    s16x8 vf10 = *(const s16x8*)&Vl[(   ln)*64 + voff[1]];
    s16x8 vf11 = *(const s16x8*)&Vl[(16+ln)*64 + voff[1]];

    const f32x4 z = {0.f,0.f,0.f,0.f};

    // QK half 1 (m 0..31 of tile) + exp/pack -> pb0
    __builtin_amdgcn_s_setprio(1);
    f32x4 s00 = MFMA_BF16(kf0, qf[0], z), s01 = MFMA_BF16(kf0, qf[1], z);
    f32x4 s02 = MFMA_BF16(kf0, qf[2], z), s03 = MFMA_BF16(kf0, qf[3], z);
    f32x4 s10 = MFMA_BF16(kf1, qf[0], z), s11 = MFMA_BF16(kf1, qf[1], z);
    f32x4 s12 = MFMA_BF16(kf1, qf[2], z), s13 = MFMA_BF16(kf1, qf[3], z);
    __builtin_amdgcn_s_setprio(0);
    s16x8 pb0[4];
    #pragma unroll
    for (int j=0;j<4;j++){
      f32x4 sa = (j==0)?s00:(j==1)?s01:(j==2)?s02:s03;
      f32x4 sc = (j==0)?s10:(j==1)?s11:(j==2)?s12:s13;
      float e0=fexp2(sa[0]), e1=fexp2(sa[1]), e2=fexp2(sa[2]), e3=fexp2(sa[3]);
      float f0=fexp2(sc[0]), f1=fexp2(sc[1]), f2=fexp2(sc[2]), f3=fexp2(sc[3]);
      psum[j] += ((e0+e1)+(e2+e3)) + ((f0+f1)+(f2+f3));
      u32x4 pw;
      pw[0]=cvtpk(e0,e1); pw[1]=cvtpk(e2,e3); pw[2]=cvtpk(f0,f1); pw[3]=cvtpk(f2,f3);
      pb0[j] = __builtin_bit_cast(s16x8, pw);
    }

    // QK half 2 (m 32..63) + exp/pack -> pb1
    __builtin_amdgcn_s_setprio(1);
    f32x4 s20 = MFMA_BF16(kf2, qf[0], z), s21 = MFMA_BF16(kf2, qf[1], z);
    f32x4 s22 = MFMA_BF16(kf2, qf[2], z), s23 = MFMA_BF16(kf2, qf[3], z);
    f32x4 s30 = MFMA_BF16(kf3, qf[0], z), s31 = MFMA_BF16(kf3, qf[1], z);
    f32x4 s32 = MFMA_BF16(kf3, qf[2], z), s33 = MFMA_BF16(kf3, qf[3], z);
    __builtin_amdgcn_s_setprio(0);
    s16x8 pb1[4];
    #pragma unroll
    for (int j=0;j<4;j++){
      f32x4 sa = (j==0)?s20:(j==1)?s21:(j==2)?s22:s23;
      f32x4 sc = (j==0)?s30:(j==1)?s31:(j==2)?s32:s33;
      float e0=fexp2(sa[0]), e1=fexp2(sa[1]), e2=fexp2(sa[2]), e3=fexp2(sa[3]);
      float f0=fexp2(sc[0]), f1=fexp2(sc[1]), f2=fexp2(sc[2]), f3=fexp2(sc[3]);
      psum[j] += ((e0+e1)+(e2+e3)) + ((f0+f1)+(f2+f3));
      u32x4 pw;
      pw[0]=cvtpk(e0,e1); pw[1]=cvtpk(e2,e3); pw[2]=cvtpk(f0,f1); pw[3]=cvtpk(f2,f3);
      pb1[j] = __builtin_bit_cast(s16x8, pw);
    }

    // PV: same k-bijection on both operands (validated R4/R7)
    __builtin_amdgcn_s_setprio(1);
    #pragma unroll
    for (int j=0;j<4;j++){
      acc[0][j] = MFMA_BF16(vf00, pb0[j], acc[0][j]);
      acc[1][j] = MFMA_BF16(vf01, pb0[j], acc[1][j]);
      acc[0][j] = MFMA_BF16(vf10, pb1[j], acc[0][j]);
      acc[1][j] = MFMA_BF16(vf11, pb1[j], acc[1][j]);
    }
    __builtin_amdgcn_s_setprio(0);
  }
  #undef ISSUE

  // ---- psum: reduce over g (lanes l, l^16, l^32, l^48 hold same n) ----
  #pragma unroll
  for (int j=0;j<4;j++){
    psum[j] += __shfl_xor(psum[j], 16, 64);
    psum[j] += __shfl_xor(psum[j], 32, 64);
  }

  // ---- 4-way combine through stage scratch ----
  asm volatile("s_waitcnt vmcnt(0)" ::: "memory");     // drain tail loads
  __syncthreads();                                     // all waves' loads landed
  float* scr = (float*)sb;                             // 3 x 64 x 36 floats
  if (w != 0){
    int base = ((w-1)*64 + lane)*36;
    #pragma unroll
    for (int ct=0; ct<2; ct++)
      #pragma unroll
      for (int j=0;j<4;j++)
        *(f32x4*)&scr[base + (ct*4+j)*4] = acc[ct][j];
    #pragma unroll
    for (int j=0;j<4;j++) scr[base+32+j] = psum[j];
  }
  __syncthreads();
  if (w == 0){
    float inv[4];
    #pragma unroll
    for (int j=0;j<4;j++){
      float ps = psum[j];
      #pragma unroll
      for (int q=0; q<3; q++) ps += scr[(q*64+lane)*36 + 32 + j];
      inv[j] = frcp(ps);
    }
    #pragma unroll
    for (int ct=0; ct<2; ct++){
      #pragma unroll
      for (int j=0;j<4;j++){
        f32x4 o = acc[ct][j];
        #pragma unroll
        for (int q=0; q<3; q++)
          o += *(const f32x4*)&scr[(q*64+lane)*36 + (ct*4+j)*4];
        unsigned lo = cvtpk(o[0]*inv[j], o[1]*inv[j]);
        unsigned hi = cvtpk(o[2]*inv[j], o[3]*inv[j]);
        unsigned long long pk = ((unsigned long long)hi<<32) | lo;
        *(unsigned long long*)&OT[(size_t)(nbase+16*j+ln)*128 + h*32 + 16*ct + 4*g] = pk;
      }
    }
  }
}

extern "C" void kernel_launch(void* const* d_in, const int* in_sizes, int n_in,
                              void* d_out, int out_size, void* d_ws, size_t ws_size,
                              hipStream_t stream)
{
  const float* feat1 = (const float*)d_in[0];
  const float* feat2 = (const float*)d_in[1];
  const float* Wq = (const float*)d_in[2];  const float* bq = (const float*)d_in[3];
  const float* Wk = (const float*)d_in[4];  const float* bk = (const float*)d_in[5];
  const float* Wv = (const float*)d_in[6];  const float* bv = (const float*)d_in[7];
  const float* Wo = (const float*)d_in[8];  const float* bo = (const float*)d_in[9];
  const float* Wg1 = (const float*)d_in[10]; const float* bg1 = (const float*)d_in[11];
  const float* Wg2 = (const float*)d_in[12]; const float* bg2 = (const float*)d_in[13];

  __hip_bfloat16* WQb  = (__hip_bfloat16*)d_ws;
  __hip_bfloat16* WKb  = WQb + 16384;
  __hip_bfloat16* WVb  = WQb + 32768;
  __hip_bfloat16* WOb  = WQb + 49152;
  __hip_bfloat16* WG1b = WQb + 65536;
  __hip_bfloat16* WG2b = WQb + 98304;
  __hip_bfloat16* F1T  = WQb + 114688;
  __hip_bfloat16* F2T  = F1T + 1048576;
  __hip_bfloat16* QT   = F1T + 2*1048576;
  __hip_bfloat16* KT   = F1T + 3*1048576;
  __hip_bfloat16* Vbf  = F1T + 4*1048576;
  __hip_bfloat16* OT   = F1T + 5*1048576;
  __hip_bfloat16* AOT  = F1T + 6*1048576;
  __hip_bfloat16* G1T  = F1T + 7*1048576;

  wprep<<<448,256,0,stream>>>(Wq,Wk,Wv,Wo,Wg1,Wg2,WQb);
  transpose2<<<dim3(128,2),256,0,stream>>>(feat1, feat2, F1T, F2T);
  qkv<<<dim3(512,3),256,0,stream>>>(F1T,F2T,WQb,bq,bk,bv,QT,KT,Vbf);
  attn10<<<dim3(128,4),256,0,stream>>>(QT,KT,Vbf,OT);
  gemmT<4,4><<<512,256,0,stream>>>(OT ,OT ,WOb ,128,bo ,1.f, AOT,0,nullptr,nullptr,nullptr);
  gemmT<8,4><<<512,256,0,stream>>>(AOT,F1T,WG1b,256,bg1,1.f, G1T,2,nullptr,nullptr,nullptr);
  gemmT<4,4><<<512,256,0,stream>>>(G1T,G1T,WG2b,128,bg2,1.f, nullptr,3,feat1,AOT,(float*)d_out);
}